// Round 6
// baseline (398.918 us; speedup 1.0000x reference)
//
#include <hip/hip_runtime.h>

// CRF forward (log partition), B=256, T=2048, N=64, MI355X.
//
// Round 13: r12 geometry + inline-asm VGPR-form MFMA.
// Post-mortem r7-r12: MfmaUtil==VALUBusy==~31% invariant across every
// structure; VGPR_Count always << live set (84 vs ~110) => compiler selects
// AGPR-form MFMA (gfx950 default), homes accumulator state in AGPRs, and
// every step pays accvgpr read/write marshal (+~90 VALU ops/step, the
// missing VALUBusy) plus MFMA<->VALU hazard wait-states on a serial
// feedback chain with only ~2-3 waves resident (~1500 dead cy/step).
// Fix: emit the 16 MFMAs of a step as ONE inline-asm block with explicit
// "v" constraints (unified file: v[] operands legal) -> all state in
// ArchVGPRs, no marshal, no AGPR hazards. Hazard padding done manually:
// s_nop 1 prologue (VALU pack -> MFMA SrcB: 2 waits), s_nop 7/7/2 epilogue
// (MFMA write -> VALU read: ~19 waits; compiler can't see inside asm).
// Everything else (32-col waves, grid 4096, LDS staging with fused exp,
// pipelined combine, bf16 fallback) byte-identical to r12.

typedef __attribute__((ext_vector_type(4))) float f32x4;
typedef __attribute__((ext_vector_type(8))) short bf16x8;

namespace {
constexpr int kB = 256;
constexpr int kT = 2048;
constexpr int kN = 64;
constexpr int kC = 8;        // chunks per sequence
constexpr int kL = kT / kC;  // 256 steps per chunk
constexpr int kStart = 1;    // GO
constexpr int kEnd = 2;      // EOS
constexpr long kTileFloats = (long)kB * kC * 4 * 1024;  // 8192 tiles x 64x16
constexpr long kNumTiles = (long)kB * kC * 4;
}  // namespace

// ---------- helpers ----------
__device__ __forceinline__ unsigned pack2bf(float lo, float hi) {
  return __builtin_amdgcn_perm(__float_as_uint(hi), __float_as_uint(lo), 0x07060302u);
}

__device__ __forceinline__ f32x4 expand2(unsigned u, unsigned v) {
  f32x4 e;
  e.x = __uint_as_float(u << 16);
  e.y = __uint_as_float(u & 0xFFFF0000u);
  e.z = __uint_as_float(v << 16);
  e.w = __uint_as_float(v & 0xFFFF0000u);
  return e;
}

__device__ __forceinline__ f32x4 exp4(f32x4 v) {
  f32x4 r;
  r.x = __expf(v.x);
  r.y = __expf(v.y);
  r.z = __expf(v.z);
  r.w = __expf(v.w);
  return r;
}

__device__ __forceinline__ float exp2i(int d) {  // 2^d for d in [-126, 127]
  return (d <= -127) ? 0.f : __uint_as_float((unsigned)(127 + d) << 23);
}

__device__ __forceinline__ float scr_rd(const char* scr, int scrStride, long F) {
  return *(const float*)(scr + (F >> 5) * (long)scrStride + (F & 31) * 4);
}

__device__ __forceinline__ bf16x8 packb(const f32x4& plo, const f32x4& phi) {
  union { unsigned u[4]; bf16x8 s; } b;
  b.u[0] = pack2bf(plo.x, plo.y);
  b.u[1] = pack2bf(plo.z, plo.w);
  b.u[2] = pack2bf(phi.x, phi.y);
  b.u[3] = pack2bf(phi.z, phi.w);
  return b.s;
}

// ---------- 32-col step, VGPR-form MFMA via inline asm ----------
// ps[nt][mt]: rows mt*16+q4*4.., cols h*32 + nt*16 + col. e fragment
// depends on (mt, q4) only -> shared by both nt chains.
// 16 MFMAs in one asm block; q outputs early-clobber so they can't alias
// the af/b/z inputs read mid-block. Dependent-C pairs are 8 instructions
// apart (>150 cy at ~19 cy/MFMA) -> no SrcC hazard.
__device__ __forceinline__ void step32(f32x4 (&ps)[2][4], const bf16x8 (&af)[4][2],
                                       const char* lrow, const f32x4 z4) {
  const f32x4 e0 = *(const f32x4*)(lrow + 0);
  const f32x4 e1 = *(const f32x4*)(lrow + 16);
  const f32x4 e2 = *(const f32x4*)(lrow + 32);
  const f32x4 e3 = *(const f32x4*)(lrow + 48);

  const bf16x8 b00 = packb(ps[0][0], ps[0][1]);  // nt0, K-half 0
  const bf16x8 b01 = packb(ps[0][2], ps[0][3]);  // nt0, K-half 1
  const bf16x8 b10 = packb(ps[1][0], ps[1][1]);  // nt1, K-half 0
  const bf16x8 b11 = packb(ps[1][2], ps[1][3]);  // nt1, K-half 1

  f32x4 q00, q01, q02, q03, q10, q11, q12, q13;
  asm volatile(
      "s_nop 1\n\t"
      "v_mfma_f32_16x16x32_bf16 %0, %8, %16, %20\n\t"
      "v_mfma_f32_16x16x32_bf16 %1, %9, %16, %20\n\t"
      "v_mfma_f32_16x16x32_bf16 %2, %10, %16, %20\n\t"
      "v_mfma_f32_16x16x32_bf16 %3, %11, %16, %20\n\t"
      "v_mfma_f32_16x16x32_bf16 %4, %8, %18, %20\n\t"
      "v_mfma_f32_16x16x32_bf16 %5, %9, %18, %20\n\t"
      "v_mfma_f32_16x16x32_bf16 %6, %10, %18, %20\n\t"
      "v_mfma_f32_16x16x32_bf16 %7, %11, %18, %20\n\t"
      "v_mfma_f32_16x16x32_bf16 %0, %12, %17, %0\n\t"
      "v_mfma_f32_16x16x32_bf16 %1, %13, %17, %1\n\t"
      "v_mfma_f32_16x16x32_bf16 %2, %14, %17, %2\n\t"
      "v_mfma_f32_16x16x32_bf16 %3, %15, %17, %3\n\t"
      "v_mfma_f32_16x16x32_bf16 %4, %12, %19, %4\n\t"
      "v_mfma_f32_16x16x32_bf16 %5, %13, %19, %5\n\t"
      "v_mfma_f32_16x16x32_bf16 %6, %14, %19, %6\n\t"
      "v_mfma_f32_16x16x32_bf16 %7, %15, %19, %7\n\t"
      "s_nop 7\n\t"
      "s_nop 7\n\t"
      "s_nop 2\n\t"
      : "=&v"(q00), "=&v"(q01), "=&v"(q02), "=&v"(q03),
        "=&v"(q10), "=&v"(q11), "=&v"(q12), "=&v"(q13)
      : "v"(af[0][0]), "v"(af[1][0]), "v"(af[2][0]), "v"(af[3][0]),
        "v"(af[0][1]), "v"(af[1][1]), "v"(af[2][1]), "v"(af[3][1]),
        "v"(b00), "v"(b01), "v"(b10), "v"(b11), "v"(z4));

  ps[0][0] = q00 * e0;
  ps[0][1] = q01 * e1;
  ps[0][2] = q02 * e2;
  ps[0][3] = q03 * e3;
  ps[1][0] = q10 * e0;
  ps[1][1] = q11 * e1;
  ps[1][2] = q12 * e2;
  ps[1][3] = q13 * e3;
}

// Renorm by exact power of 2 from lane 0's ps[0][0].x exponent.
// Spread bounded (~2^21); 4-step growth <= 2^56 -> max < 2^78, safe.
__device__ __forceinline__ void renorm32(f32x4 (&ps)[2][4], float& tot_e) {
  const unsigned eref = __builtin_amdgcn_readfirstlane(__float_as_uint(ps[0][0].x));
  const int e = (int)((eref >> 23) & 0xFFu) - 127;
  const float sc = __uint_as_float((unsigned)(127 - e) << 23);
#pragma unroll
  for (int nt = 0; nt < 2; ++nt)
#pragma unroll
    for (int mt = 0; mt < 4; ++mt) ps[nt][mt] *= sc;
  tot_e += (float)e;
}

// ---------- chunk kernel: 1 wave = 32 columns of one chunk ----------
__global__ __launch_bounds__(64, 3) void chunk32_kernel(
    const char* __restrict__ un, const float* __restrict__ trans,
    const int* __restrict__ lengths, char* __restrict__ scr, int scrStride) {
  const int bid = blockIdx.x;
  const int b = bid >> 4;
  const int c = (bid >> 1) & 7;
  const int h = bid & 1;  // column half
  const int len = lengths[b];
  const int start = c * kL;
  int steps = len - start;
  if (steps <= 0) return;
  if (steps > kL) steps = kL;

  const int lane = threadIdx.x & 63;
  const int col = lane & 15;
  const int q4 = lane >> 4;

  // Static A-fragments, psi-permuted K (verified rounds 2-12).
  bf16x8 af[4][2];
#pragma unroll
  for (int mt = 0; mt < 4; ++mt) {
#pragma unroll
    for (int kc = 0; kc < 2; ++kc) {
      union { unsigned u[4]; bf16x8 s; } fr;
#pragma unroll
      for (int jp = 0; jp < 4; ++jp) {
        const int j0 = 2 * jp, j1 = 2 * jp + 1;
        const int k0 = (2 * kc + (j0 >> 2)) * 16 + q4 * 4 + (j0 & 3);
        const int k1 = (2 * kc + (j1 >> 2)) * 16 + q4 * 4 + (j1 & 3);
        unsigned e0 = __float_as_uint(__expf(trans[(mt * 16 + col) * kN + k0])) + 0x8000u;
        unsigned e1 = __float_as_uint(__expf(trans[(mt * 16 + col) * kN + k1])) + 0x8000u;
        fr.u[jp] = __builtin_amdgcn_perm(e1, e0, 0x07060302u);
      }
      af[mt][kc] = fr.s;
    }
  }

  const f32x4 z4 = {0.f, 0.f, 0.f, 0.f};

  // Acc = identity columns h*32 + nt*16 + col.
  f32x4 ps[2][4];
#pragma unroll
  for (int nt = 0; nt < 2; ++nt) {
    const int mycol = h * 32 + nt * 16 + col;
#pragma unroll
    for (int mt = 0; mt < 4; ++mt) {
      const int rb = mt * 16 + q4 * 4;
      f32x4 v;
      v.x = (rb + 0 == mycol) ? 1.f : 0.f;
      v.y = (rb + 1 == mycol) ? 1.f : 0.f;
      v.z = (rb + 2 == mycol) ? 1.f : 0.f;
      v.w = (rb + 3 == mycol) ? 1.f : 0.f;
      ps[nt][mt] = v;
    }
  }

  // Per-wave staging (verbatim r11/r12): 16 raw unary rows per stage, exp +
  // psi-permute en route (psi moves 16B groups as units). No barriers.
  const char* gbase = un + (size_t)(b * kT + start) * 256;
  const int srow = lane >> 2;  // 0..15
  const int sb = lane & 3;     // 0..3
  const size_t gRow = (size_t)srow * 256;

  __shared__ __align__(16) char sm[2][4096];

  {  // preload stage 0
    const char* g = gbase + gRow + sb * 16;
    f32x4 v0 = exp4(*(const f32x4*)(g + 0));
    f32x4 v1 = exp4(*(const f32x4*)(g + 64));
    f32x4 v2 = exp4(*(const f32x4*)(g + 128));
    f32x4 v3 = exp4(*(const f32x4*)(g + 192));
    char* l = &sm[0][0] + gRow + (size_t)sb * 64;
    *(f32x4*)(l + 0) = v0;
    *(f32x4*)(l + 16) = v1;
    *(f32x4*)(l + 32) = v2;
    *(f32x4*)(l + 48) = v3;
  }

  float tot_e = 0.0f;
  const int nst = (steps + 15) >> 4;
  for (int s = 0; s < nst; ++s) {
    f32x4 v0, v1, v2, v3;
    const bool more = (s + 1 < nst);
    if (more) {  // issue next stage's raw loads now; consume after compute
      const char* g = gbase + (size_t)(s + 1) * 4096 + gRow + sb * 16;
      v0 = *(const f32x4*)(g + 0);
      v1 = *(const f32x4*)(g + 64);
      v2 = *(const f32x4*)(g + 128);
      v3 = *(const f32x4*)(g + 192);
    }

    int ns = steps - s * 16;
    ns = ns > 16 ? 16 : ns;
    const char* lb = &sm[s & 1][0] + q4 * 64;
    if (ns == 16) {
      const char* l2 = lb;
#pragma unroll 1
      for (int g4 = 0; g4 < 4; ++g4) {
        step32(ps, af, l2 + 0, z4);
        step32(ps, af, l2 + 256, z4);
        step32(ps, af, l2 + 512, z4);
        step32(ps, af, l2 + 768, z4);
        renorm32(ps, tot_e);
        l2 += 1024;
      }
    } else {
      for (int i = 0; i < ns; ++i) {
        step32(ps, af, lb + (size_t)i * 256, z4);
        if ((i & 3) == 3) renorm32(ps, tot_e);
      }
    }

    if (more) {
      char* l = &sm[(s + 1) & 1][0] + gRow + (size_t)sb * 64;
      *(f32x4*)(l + 0) = exp4(v0);
      *(f32x4*)(l + 16) = exp4(v1);
      *(f32x4*)(l + 32) = exp4(v2);
      *(f32x4*)(l + 48) = exp4(v3);
    }
  }

  // Store 2 x (64x16) tiles, flat F = tile*1024 + col*64 + row -> slots of
  // 32 floats, byte stride scrStride. Per-tile tot_e.
  const long tbase = ((long)b * kC + c) * 4 + h * 2;
#pragma unroll
  for (int nt = 0; nt < 2; ++nt) {
    const long tileIdx = tbase + nt;
#pragma unroll
    for (int mt = 0; mt < 4; ++mt) {
      const long slot = tileIdx * 32 + col * 2 + (mt >> 1);
      char* addr = scr + slot * (long)scrStride + ((mt & 1) * 16 + q4 * 4) * 4;
      *(f32x4*)addr = ps[nt][mt];
    }
    if (lane == 0) {
      const long F = kTileFloats + tileIdx;
      *(float*)(scr + (F >> 5) * (long)scrStride + (F & 31) * 4) = tot_e;
    }
  }
}

// ---------- combine: chain chunk matrices, prefetched ping-pong ----------
__device__ __forceinline__ void load_mat(const char* scr, int scrStride, long tb,
                                         int j, float (&m)[4][16], float (&ev)[4]) {
#pragma unroll
  for (int s = 0; s < 4; ++s) {
#pragma unroll
    for (int k = 0; k < 16; ++k)
      m[s][k] = scr_rd(scr, scrStride, (tb + s) * 1024 + (long)k * 64 + j);
    ev[s] = scr_rd(scr, scrStride, kTileFloats + tb + s);
  }
}

__global__ __launch_bounds__(64, 1) void combine_kernel(
    const char* __restrict__ scr, int scrStride, const float* __restrict__ trans,
    const int* __restrict__ lengths, float* __restrict__ out) {
  const int b = blockIdx.x;
  const int j = threadIdx.x;
  const int len = lengths[b];

  // alpha after chunk 0 = column kStart of chunk-0 matrix.
  const long t0 = (long)b * kC * 4;
  float a = scr_rd(scr, scrStride, t0 * 1024 + kStart * 64 + j);
  float totE = scr_rd(scr, scrStride, kTileFloats + t0);

  float mc[4][16], ec[4];
  load_mat(scr, scrStride, t0 + 4, j, mc, ec);  // chunk 1

#pragma unroll
  for (int c = 1; c < kC; ++c) {
    float mn[4][16], en[4];
    if (c + 1 < kC)  // prefetch chunk c+1 while chaining chunk c
      load_mat(scr, scrStride, t0 + (long)(c + 1) * 4, j, mn, en);

    if (c * kL < len) {  // chunks are contiguous-active
      float s0 = 0.f, s1 = 0.f, s2 = 0.f, s3 = 0.f;
#pragma unroll
      for (int k16 = 0; k16 < 16; ++k16) {
        const float a0 = __int_as_float(__builtin_amdgcn_readlane(__float_as_int(a), k16));
        const float a1 = __int_as_float(__builtin_amdgcn_readlane(__float_as_int(a), 16 + k16));
        const float a2 = __int_as_float(__builtin_amdgcn_readlane(__float_as_int(a), 32 + k16));
        const float a3 = __int_as_float(__builtin_amdgcn_readlane(__float_as_int(a), 48 + k16));
        s0 = fmaf(mc[0][k16], a0, s0);
        s1 = fmaf(mc[1][k16], a1, s1);
        s2 = fmaf(mc[2][k16], a2, s2);
        s3 = fmaf(mc[3][k16], a3, s3);
      }
      const float em = fmaxf(fmaxf(ec[0], ec[1]), fmaxf(ec[2], ec[3]));
      a = s0 * exp2i((int)(ec[0] - em)) + s1 * exp2i((int)(ec[1] - em)) +
          s2 * exp2i((int)(ec[2] - em)) + s3 * exp2i((int)(ec[3] - em));
      totE += em;

      // renorm alpha (exact power of 2 from the wave max)
      float m = a;
#pragma unroll
      for (int mask = 1; mask < 64; mask <<= 1) m = fmaxf(m, __shfl_xor(m, mask));
      const int e = (int)((__float_as_uint(m) >> 23) & 0xFFu) - 127;
      a *= exp2i(-e);
      totE += (float)e;
    }

    if (c + 1 < kC) {  // ping-pong (SSA renames under full unroll)
#pragma unroll
      for (int s = 0; s < 4; ++s) {
#pragma unroll
        for (int k = 0; k < 16; ++k) mc[s][k] = mn[s][k];
        ec[s] = en[s];
      }
    }
  }

  float term = a * __expf(trans[kEnd * kN + j]);
#pragma unroll
  for (int mask = 1; mask < 64; mask <<= 1) term += __shfl_xor(term, mask);

  if (j == 0) out[b] = totE * 0.69314718055994530942f + logf(term);
}

// ================= fallback machinery (ws < scratch): r10/r11 path =========
__global__ void exp_swizzle_bf16(const float* in, char* outbase) {
  const int total = kB * kT * 32;  // pairs
  int p = blockIdx.x * blockDim.x + threadIdx.x;
  const int stride = gridDim.x * blockDim.x;
  for (; p < total; p += stride) {
    const int r = p >> 5;
    const int j0 = (p & 31) << 1;
    const float2 v = *(const float2*)(in + (size_t)r * kN + j0);
    const float e0 = __expf(v.x), e1 = __expf(v.y);
    unsigned u0 = __float_as_uint(e0);
    u0 += 0x7FFFu + ((u0 >> 16) & 1u);  // RNE to bf16
    unsigned u1 = __float_as_uint(e1);
    u1 += 0x7FFFu + ((u1 >> 16) & 1u);
    const unsigned d = (u1 & 0xFFFF0000u) | (u0 >> 16);
    const int pi = ((j0 >> 2) & 3) * 16 + ((j0 >> 4) << 2) + (j0 & 3);
    *(unsigned*)(outbase + (size_t)r * 256 + pi * 2) = d;
  }
}

__device__ __forceinline__ void step_lds_bf16(f32x4 (&ps)[4], const bf16x8 (&af)[4][2],
                                              const char* lrow) {
  const uint4 u0 = *(const uint4*)(lrow + 0);
  const uint4 u1 = *(const uint4*)(lrow + 16);
  f32x4 e0 = expand2(u0.x, u0.y);
  f32x4 e1 = expand2(u0.z, u0.w);
  f32x4 e2 = expand2(u1.x, u1.y);
  f32x4 e3 = expand2(u1.z, u1.w);

  union { unsigned u[4]; bf16x8 s; } b0u, b1u;
  b0u.u[0] = pack2bf(ps[0].x, ps[0].y);
  b0u.u[1] = pack2bf(ps[0].z, ps[0].w);
  b0u.u[2] = pack2bf(ps[1].x, ps[1].y);
  b0u.u[3] = pack2bf(ps[1].z, ps[1].w);
  const bf16x8 b0 = b0u.s;
  const f32x4 z4 = {0.f, 0.f, 0.f, 0.f};
  f32x4 q0 = __builtin_amdgcn_mfma_f32_16x16x32_bf16(af[0][0], b0, z4, 0, 0, 0);
  f32x4 q1 = __builtin_amdgcn_mfma_f32_16x16x32_bf16(af[1][0], b0, z4, 0, 0, 0);
  f32x4 q2 = __builtin_amdgcn_mfma_f32_16x16x32_bf16(af[2][0], b0, z4, 0, 0, 0);
  f32x4 q3 = __builtin_amdgcn_mfma_f32_16x16x32_bf16(af[3][0], b0, z4, 0, 0, 0);
  b1u.u[0] = pack2bf(ps[2].x, ps[2].y);
  b1u.u[1] = pack2bf(ps[2].z, ps[2].w);
  b1u.u[2] = pack2bf(ps[3].x, ps[3].y);
  b1u.u[3] = pack2bf(ps[3].z, ps[3].w);
  const bf16x8 b1 = b1u.s;
  q0 = __builtin_amdgcn_mfma_f32_16x16x32_bf16(af[0][1], b1, q0, 0, 0, 0);
  q1 = __builtin_amdgcn_mfma_f32_16x16x32_bf16(af[1][1], b1, q1, 0, 0, 0);
  q2 = __builtin_amdgcn_mfma_f32_16x16x32_bf16(af[2][1], b1, q2, 0, 0, 0);
  q3 = __builtin_amdgcn_mfma_f32_16x16x32_bf16(af[3][1], b1, q3, 0, 0, 0);

  ps[0] = q0 * e0;
  ps[1] = q1 * e1;
  ps[2] = q2 * e2;
  ps[3] = q3 * e3;
}

__device__ __forceinline__ void renorm16(f32x4 (&ps)[4], float& tot_e) {
  const unsigned eref = __builtin_amdgcn_readfirstlane(__float_as_uint(ps[0].x));
  const int e = (int)((eref >> 23) & 0xFFu) - 127;
  const float sc = __uint_as_float((unsigned)(127 - e) << 23);
#pragma unroll
  for (int mt = 0; mt < 4; ++mt) ps[mt] *= sc;
  tot_e += (float)e;
}

__global__ __launch_bounds__(256, 3) void chunk_pair_bf16_kernel(
    const char* __restrict__ eu, const float* __restrict__ trans,
    const int* __restrict__ lengths, char* __restrict__ scr, int scrStride) {
  constexpr int RB = 128;
  constexpr int SEG = RB / 8;
  constexpr int STG = 32 * RB;

  const int b = blockIdx.x >> 2;
  const int cp = blockIdx.x & 3;
  const int len = lengths[b];
  const int cA = 2 * cp, cB = 2 * cp + 1;
  int stepsA = len - cA * kL;
  stepsA = stepsA < 0 ? 0 : (stepsA > kL ? kL : stepsA);
  int stepsB = len - cB * kL;
  stepsB = stepsB < 0 ? 0 : (stepsB > kL ? kL : stepsB);
  if (stepsA <= 0) return;

  const int t8 = threadIdx.x;
  const int lane = t8 & 63;
  const int w = t8 >> 6;
  const int col = lane & 15;
  const int q4 = lane >> 4;

  bf16x8 af[4][2];
#pragma unroll
  for (int mt = 0; mt < 4; ++mt) {
#pragma unroll
    for (int kc = 0; kc < 2; ++kc) {
      union { unsigned u[4]; bf16x8 s; } fr;
#pragma unroll
      for (int jp = 0; jp < 4; ++jp) {
        const int j0 = 2 * jp, j1 = 2 * jp + 1;
        const int k0 = (2 * kc + (j0 >> 2)) * 16 + q4 * 4 + (j0 & 3);
        const int k1 = (2 * kc + (j1 >> 2)) * 16 + q4 * 4 + (j1 & 3);
        unsigned e0 = __float_as_uint(__expf(trans[(mt * 16 + col) * kN + k0])) + 0x8000u;
        unsigned e1 = __float_as_uint(__expf(trans[(mt * 16 + col) * kN + k1])) + 0x8000u;
        fr.u[jp] = __builtin_amdgcn_perm(e1, e0, 0x07060302u);
      }
      af[mt][kc] = fr.s;
    }
  }

  const int mycol = w * 16 + col;
  f32x4 psA[4], psB[4];
#pragma unroll
  for (int mt = 0; mt < 4; ++mt) {
    const int rb = mt * 16 + q4 * 4;
    f32x4 v;
    v.x = (rb + 0 == mycol) ? 1.f : 0.f;
    v.y = (rb + 1 == mycol) ? 1.f : 0.f;
    v.z = (rb + 2 == mycol) ? 1.f : 0.f;
    v.w = (rb + 3 == mycol) ? 1.f : 0.f;
    psA[mt] = v;
    psB[mt] = v;
  }

  const char* gblkA = eu + (size_t)(b * kT + cA * kL) * 256;
  const char* gblkB = eu + (size_t)(b * kT + cB * kL) * 256;
  const size_t gOff = (size_t)(t8 >> 3) * 256 + (size_t)(t8 & 7) * SEG;
  const size_t lOff = (size_t)(t8 >> 3) * RB + (size_t)(t8 & 7) * SEG;

  __shared__ __align__(16) char smem[2][2][STG];

  {
    uint4 vaA = *(const uint4*)(gblkA + gOff);
    uint4 vaB = *(const uint4*)(gblkB + gOff);
    *(uint4*)(&smem[0][0][0] + lOff) = vaA;
    *(uint4*)(&smem[1][0][0] + lOff) = vaB;
  }
  __syncthreads();

  float totA = 0.0f, totB = 0.0f;
  for (int s = 0; s < 8; ++s) {
    uint4 vaA, vaB;
    const bool more = (s < 7);
    if (more) {
      vaA = *(const uint4*)(gblkA + (size_t)(s + 1) * 8192 + gOff);
      vaB = *(const uint4*)(gblkB + (size_t)(s + 1) * 8192 + gOff);
    }

    int nsA = stepsA - s * 32;
    nsA = nsA < 0 ? 0 : (nsA > 32 ? 32 : nsA);
    int nsB = stepsB - s * 32;
    nsB = nsB < 0 ? 0 : (nsB > 32 ? 32 : nsB);
    const char* lbA = &smem[0][s & 1][0] + q4 * (RB / 4);
    const char* lbB = &smem[1][s & 1][0] + q4 * (RB / 4);

    if (nsA == 32 && nsB == 32) {
      for (int g = 0; g < 8; ++g) {
#pragma unroll
        for (int k = 0; k < 4; ++k) {
          step_lds_bf16(psA, af, lbA + (g * 4 + k) * RB);
          step_lds_bf16(psB, af, lbB + (g * 4 + k) * RB);
        }
        renorm16(psA, totA);
        renorm16(psB, totB);
      }
    } else {
      for (int i = 0; i < nsA; ++i) {
        step_lds_bf16(psA, af, lbA + (size_t)i * RB);
        if ((i & 3) == 3) renorm16(psA, totA);
      }
      for (int i = 0; i < nsB; ++i) {
        step_lds_bf16(psB, af, lbB + (size_t)i * RB);
        if ((i & 3) == 3) renorm16(psB, totB);
      }
    }

    if (more) {
      *(uint4*)(&smem[0][(s + 1) & 1][0] + lOff) = vaA;
      *(uint4*)(&smem[1][(s + 1) & 1][0] + lOff) = vaB;
    }
    __syncthreads();
  }

  {
    const long tileIdx = ((long)b * kC + cA) * 4 + w;
#pragma unroll
    for (int mt = 0; mt < 4; ++mt) {
      const long slot = tileIdx * 32 + col * 2 + (mt >> 1);
      char* addr = scr + slot * (long)scrStride + ((mt & 1) * 16 + q4 * 4) * 4;
      *(f32x4*)addr = psA[mt];
    }
    if (lane == 0) {
      const long F = kTileFloats + tileIdx;
      *(float*)(scr + (F >> 5) * (long)scrStride + (F & 31) * 4) = totA;
    }
  }
  if (stepsB > 0) {
    const long tileIdx = ((long)b * kC + cB) * 4 + w;
#pragma unroll
    for (int mt = 0; mt < 4; ++mt) {
      const long slot = tileIdx * 32 + col * 2 + (mt >> 1);
      char* addr = scr + slot * (long)scrStride + ((mt & 1) * 16 + q4 * 4) * 4;
      *(f32x4*)addr = psB[mt];
    }
    if (lane == 0) {
      const long F = kTileFloats + tileIdx;
      *(float*)(scr + (F >> 5) * (long)scrStride + (F & 31) * 4) = totB;
    }
  }
}

extern "C" void kernel_launch(void* const* d_in, const int* in_sizes, int n_in,
                              void* d_out, int out_size, void* d_ws, size_t ws_size,
                              hipStream_t stream) {
  const float* unary = (const float*)d_in[0];  // [B, T, N] fp32, 128 MiB
  const float* trans = (const float*)d_in[1];  // [N, N] fp32
  const int* lengths = (const int*)d_in[2];    // [B] int32
  float* out = (float*)d_out;                  // [B] fp32

  const size_t scrBytes = (size_t)(kTileFloats + kNumTiles) * 4;  // ~33.6 MB

  if (ws_size >= scrBytes) {
    // Primary: read raw unary directly (exp fused into staging); tiles in
    // workspace; inputs never written.
    chunk32_kernel<<<dim3(kB * kC * 2), dim3(64), 0, stream>>>(
        (const char*)d_in[0], trans, lengths, (char*)d_ws, 128);
    combine_kernel<<<dim3(kB), dim3(64), 0, stream>>>((const char*)d_ws, 128,
                                                      trans, lengths, out);
  } else {
    // Fallback: bf16 eu in lower 128 B of each 256-B row of d_in[0]; tiles
    // in the upper 128 B halves (byte-disjoint; harness restores inputs).
    exp_swizzle_bf16<<<dim3(4096), dim3(256), 0, stream>>>(unary, (char*)d_in[0]);
    chunk_pair_bf16_kernel<<<dim3(kB * 4), dim3(256), 0, stream>>>(
        (const char*)d_in[0], trans, lengths, (char*)d_in[0] + 128, 256);
    combine_kernel<<<dim3(kB), dim3(64), 0, stream>>>((const char*)d_in[0] + 128,
                                                      256, trans, lengths, out);
  }
}